// Round 4
// baseline (389.723 us; speedup 1.0000x reference)
//
#include <hip/hip_runtime.h>
#include <math.h>

#define NBINS 15
#define NCLS 100
#define ECE_EPS 1e-5f

// s_waitcnt imm encodings (gfx9/CDNA): vmcnt bits[3:0]+[15:14], expcnt [6:4], lgkmcnt [11:8].
// WAIT_VM25 = wait until <=25 VMEM outstanding (keep next chunk's 25 stages in flight).
// WAIT_VM0  = full VMEM drain (last chunk). lgkm/exp fields maxed = don't wait.
#define WAIT_VM25 0x4F79
#define WAIT_VM0  0x0F70

// Kernel A: one wave per block; double-buffered 64-row chunks staged via
// global_load_lds (25 x 1KB coalesced). While computing chunk k from LDS buf b,
// chunk k+1's loads are in flight into buf b^1 (vmcnt(25) partial wait).
// Lane L processes row L of the chunk; per-lane read order rotated by (L>>3)
// to reduce the 400B-row-stride LDS bank conflict from 8-way to ~2-way.
__global__ __launch_bounds__(64) void ece_hist(const float* __restrict__ logits,
                                               const int* __restrict__ labels,
                                               int* __restrict__ g_cnt,
                                               float* __restrict__ g_acc,
                                               int n_rows) {
    __shared__ float s_rows[2][64 * NCLS];   // 2 x 25.6 KB staging buffers
    __shared__ int   s_cnt[NCLS];
    __shared__ float s_accs[NCLS];

    const int lane = threadIdx.x;            // 0..63, single wave per block
    #pragma unroll
    for (int i = lane; i < NCLS; i += 64) { s_cnt[i] = 0; s_accs[i] = 0.0f; }

    const int n_chunks = n_rows >> 6;
    const int rot = (lane >> 3) & 7;         // bank-conflict rotation

    // stage first chunk into buf 0
    int chunk = blockIdx.x;
    if (chunk < n_chunks) {
        const float* gbase = logits + (size_t)chunk * (64 * NCLS);
        #pragma unroll
        for (int j = 0; j < 25; ++j) {
            __builtin_amdgcn_global_load_lds(
                (const __attribute__((address_space(1))) void*)(gbase + (size_t)(j * 64 + lane) * 4),
                (__attribute__((address_space(3))) void*)(&s_rows[0][j * 256]),
                16, 0, 0);
        }
    }

    int buf = 0;
    while (chunk < n_chunks) {
        const int next = chunk + gridDim.x;
        const int lab = labels[chunk * 64 + lane];     // compiler tracks its own wait
        if (next < n_chunks) {
            const float* gbase = logits + (size_t)next * (64 * NCLS);
            #pragma unroll
            for (int j = 0; j < 25; ++j) {
                __builtin_amdgcn_global_load_lds(
                    (const __attribute__((address_space(1))) void*)(gbase + (size_t)(j * 64 + lane) * 4),
                    (__attribute__((address_space(3))) void*)(&s_rows[buf ^ 1][j * 256]),
                    16, 0, 0);
            }
            __builtin_amdgcn_s_waitcnt(WAIT_VM25);     // current chunk's stages complete
        } else {
            __builtin_amdgcn_s_waitcnt(WAIT_VM0);
        }

        const float4* __restrict__ rp = (const float4*)&s_rows[buf][lane * NCLS];

        // ---- pass 1: max/argmax (rotated order; explicit lowest-index tie-break) ----
        float m = -INFINITY; int mi = 1 << 30;
        #pragma unroll
        for (int j = 0; j < 25; ++j) {
            int jj = j + rot; jj -= (jj >= 25) ? 25 : 0;
            const float4 x = rp[jj];
            const int base = 4 * jj;
            if (x.x > m || (x.x == m && base     < mi)) { m = x.x; mi = base;     }
            if (x.y > m || (x.y == m && base + 1 < mi)) { m = x.y; mi = base + 1; }
            if (x.z > m || (x.z == m && base + 2 < mi)) { m = x.z; mi = base + 2; }
            if (x.w > m || (x.w == m && base + 3 < mi)) { m = x.w; mi = base + 3; }
        }

        // ---- pass 2: sum exp(x - m) ----
        float s0 = 0.0f, s1 = 0.0f, s2 = 0.0f, s3 = 0.0f;
        #pragma unroll
        for (int j = 0; j < 25; ++j) {
            int jj = j + rot; jj -= (jj >= 25) ? 25 : 0;
            const float4 x = rp[jj];
            s0 += __expf(x.x - m);
            s1 += __expf(x.y - m);
            s2 += __expf(x.z - m);
            s3 += __expf(x.w - m);
        }
        const float pred = -__logf((s0 + s1) + (s2 + s3));   // max of log_softmax

        atomicAdd(&s_cnt[mi], 1);
        if (pred == (float)lab) atomicAdd(&s_accs[mi], 1.0f);  // faithful; ~never taken

        buf ^= 1;
        chunk = next;
    }

    // ---- tail rows (n_rows % 64), block 0 only ----
    const int tail_start = n_chunks << 6;
    if (blockIdx.x == 0 && tail_start + lane < n_rows) {
        const float* row = logits + (size_t)(tail_start + lane) * NCLS;
        float m = -INFINITY; int mi = 0;
        for (int c = 0; c < NCLS; ++c) { const float x = row[c]; if (x > m) { m = x; mi = c; } }
        float s = 0.0f;
        for (int c = 0; c < NCLS; ++c) s += __expf(row[c] - m);
        const float pred = -__logf(s);
        atomicAdd(&s_cnt[mi], 1);
        if (pred == (float)labels[tail_start + lane]) atomicAdd(&s_accs[mi], 1.0f);
    }

    // single wave per block: LDS atomics above are wave-ordered; no barrier needed
    #pragma unroll
    for (int i = lane; i < NCLS; i += 64) {
        if (s_cnt[i])          atomicAdd(&g_cnt[i], s_cnt[i]);
        if (s_accs[i] != 0.0f) atomicAdd(&g_acc[i], s_accs[i]);
    }
}

// Kernel B: fold the 100-entry histogram into the 15-bin sums and the final scalar.
// coeff(c,b) = softmax_b( -(c - anchor_b)^2 / 0.01 ), identical math to reference.
__global__ void ece_final(const int* __restrict__ g_cnt,
                          const float* __restrict__ g_acc,
                          float* __restrict__ out) {
    __shared__ float s_bins[3 * NBINS];
    const int tid = threadIdx.x;
    if (tid < 3 * NBINS) s_bins[tid] = 0.0f;
    __syncthreads();

    if (tid < NCLS) {
        const float cnt  = (float)g_cnt[tid];
        const float accv = g_acc[tid];
        const float conf = (float)tid;
        float diff[NBINS];
        float dm = -INFINITY;
        #pragma unroll
        for (int b = 0; b < NBINS; ++b) {
            const float a = (float)(2 * b + 1) * (1.0f / 30.0f);
            const float d = conf - a;
            diff[b] = -(d * d) * 100.0f;
            dm = fmaxf(dm, diff[b]);
        }
        float es = 0.0f;
        float e[NBINS];
        #pragma unroll
        for (int b = 0; b < NBINS; ++b) { e[b] = __expf(diff[b] - dm); es += e[b]; }
        const float inv = 1.0f / es;
        #pragma unroll
        for (int b = 0; b < NBINS; ++b) {
            const float coeff = e[b] * inv;
            atomicAdd(&s_bins[b],             cnt * coeff);
            atomicAdd(&s_bins[NBINS + b],     conf * cnt * coeff);
            atomicAdd(&s_bins[2 * NBINS + b], accv * coeff);
        }
    }
    __syncthreads();

    if (tid == 0) {
        float total = 0.0f;
        #pragma unroll
        for (int b = 0; b < NBINS; ++b) total += fabsf(s_bins[b]);
        const float invw = 1.0f / fmaxf(total, ECE_EPS);
        float ece = 0.0f;
        #pragma unroll
        for (int b = 0; b < NBINS; ++b) {
            const float sc = s_bins[b];
            const float denom = fmaxf(sc, ECE_EPS);
            const float bc = s_bins[NBINS + b] / denom;
            const float ba = s_bins[2 * NBINS + b] / denom;
            const float d  = bc - ba;
            ece += d * d * (sc * invw);
        }
        out[0] = sqrtf(ece);
    }
}

extern "C" void kernel_launch(void* const* d_in, const int* in_sizes, int n_in,
                              void* d_out, int out_size, void* d_ws, size_t ws_size,
                              hipStream_t stream) {
    const float* logits = (const float*)d_in[0];
    const int*   labels = (const int*)d_in[1];
    int*   g_cnt = (int*)d_ws;
    float* g_acc = (float*)((char*)d_ws + NCLS * sizeof(int));
    float* outp  = (float*)d_out;
    const int n_rows = in_sizes[1];   // labels element count = N

    hipMemsetAsync(d_ws, 0, NCLS * (sizeof(int) + sizeof(float)), stream);
    // 52 KB LDS/block -> 3 single-wave blocks resident per CU; 768 = 3 x 256 CUs.
    // N=524288 -> 8192 chunks -> 10-11 chunks per block, balanced across the
    // resident set (no straggler second tranche as 1024 blocks would cause).
    ece_hist<<<768, 64, 0, stream>>>(logits, labels, g_cnt, g_acc, n_rows);
    ece_final<<<1, 128, 0, stream>>>(g_cnt, g_acc, outp);
}